// Round 8
// baseline (392.407 us; speedup 1.0000x reference)
//
#include <hip/hip_runtime.h>

#define DI __device__ __forceinline__

typedef _Float16 f16x8 __attribute__((ext_vector_type(8)));
typedef _Float16 f16x4 __attribute__((ext_vector_type(4)));
typedef float    f32x4 __attribute__((ext_vector_type(4)));

namespace {

constexpr int kB  = 8;
constexpr int kMQ = 512;
constexpr int kMK = 2048;
constexpr int kQKC = 1024;   // = H*DQ
constexpr int kVC  = 1024;   // = H*DV

DI void gload16(const void* g, void* l) {
  __builtin_amdgcn_global_load_lds(
      (const __attribute__((address_space(1))) void*)g,
      (__attribute__((address_space(3))) void*)l, 16, 0, 0);
}

DI f32x4 mfma16(f16x8 a, f16x8 b, f32x4 c) {
  return __builtin_amdgcn_mfma_f32_16x16x32_f16(a, b, c, 0, 0, 0);
}

DI f32x4 mfma16k16(f16x4 a, f16x4 b, f32x4 c) {
  return __builtin_amdgcn_mfma_f32_16x16x16f16(a, b, c, 0, 0, 0);
}

// ================= unified prep: 3 weight transposes + 2 LayerNorms + worklist =====
template<int K, int N>
DI void transpose_dev(const float* __restrict__ W, _Float16* __restrict__ WT,
                      int bid, float (*t)[65]) {
  int nt = bid % (N / 64), kt = bid / (N / 64);
  int k0 = kt * 64, n0 = nt * 64;
  int tid = threadIdx.x;
#pragma unroll
  for (int j = 0; j < 16; ++j) {
    int e = tid + j * 256;
    int r = e >> 6, c = e & 63;
    t[r][c] = W[(size_t)(k0 + r) * N + n0 + c];
  }
  __syncthreads();
#pragma unroll
  for (int j = 0; j < 16; ++j) {
    int e = tid + j * 256;
    int r = e >> 6, c = e & 63;
    WT[(size_t)(n0 + r) * K + k0 + c] = (_Float16)t[c][r];
  }
}

DI void ln1024_dev(const float* __restrict__ x, const float* __restrict__ w,
                   const float* __restrict__ bb, _Float16* __restrict__ y,
                   int row, float* red) {
  int tid = threadIdx.x;
  const float4* xr = (const float4*)(x + (size_t)row * 1024);
  float4 v = xr[tid];
  float s = v.x + v.y + v.z + v.w;
  float q = v.x * v.x + v.y * v.y + v.z * v.z + v.w * v.w;
#pragma unroll
  for (int m = 32; m; m >>= 1) { s += __shfl_xor(s, m); q += __shfl_xor(q, m); }
  if ((tid & 63) == 0) { red[tid >> 6] = s; red[4 + (tid >> 6)] = q; }
  __syncthreads();
  s = red[0] + red[1] + red[2] + red[3];
  q = red[4] + red[5] + red[6] + red[7];
  float mean = s * (1.0f / 1024.0f);
  float var = q * (1.0f / 1024.0f) - mean * mean;
  float inv = rsqrtf(var + 1e-5f);
  f16x4 o;
  const float* wp = w + tid * 4;
  const float* bp = bb + tid * 4;
  o[0] = (_Float16)((v.x - mean) * inv * wp[0] + bp[0]);
  o[1] = (_Float16)((v.y - mean) * inv * wp[1] + bp[1]);
  o[2] = (_Float16)((v.z - mean) * inv * wp[2] + bp[2]);
  o[3] = (_Float16)((v.w - mean) * inv * wp[3] + bp[3]);
  *(f16x4*)(y + (size_t)row * 1024 + tid * 4) = o;
}

DI void ln256_dev(const float* __restrict__ x, const float* __restrict__ w,
                  const float* __restrict__ bb, _Float16* __restrict__ y, int bid) {
  int tid = threadIdx.x;
  int lane = tid & 63, wv = tid >> 6;
  size_t row = (size_t)bid * 4 + wv;
  const float4* xr = (const float4*)(x + row * 256);
  float4 v = xr[lane];
  float s = v.x + v.y + v.z + v.w;
  float q = v.x * v.x + v.y * v.y + v.z * v.z + v.w * v.w;
#pragma unroll
  for (int m = 32; m; m >>= 1) { s += __shfl_xor(s, m); q += __shfl_xor(q, m); }
  float mean = s * (1.0f / 256.0f);
  float var = q * (1.0f / 256.0f) - mean * mean;
  float inv = rsqrtf(var + 1e-5f);
  f16x4 o;
  const float* wp = w + lane * 4;
  const float* bp = bb + lane * 4;
  o[0] = (_Float16)((v.x - mean) * inv * wp[0] + bp[0]);
  o[1] = (_Float16)((v.y - mean) * inv * wp[1] + bp[1]);
  o[2] = (_Float16)((v.z - mean) * inv * wp[2] + bp[2]);
  o[3] = (_Float16)((v.w - mean) * inv * wp[3] + bp[3]);
  *(f16x4*)(y + row * 256 + lane * 4) = o;
}

__global__ __launch_bounds__(256) void prep_all(
    const float* __restrict__ Wq, const float* __restrict__ Wk, const float* __restrict__ Wv,
    _Float16* __restrict__ WqT, _Float16* __restrict__ WkT, _Float16* __restrict__ WvT,
    const float* __restrict__ hs, const float* __restrict__ ln1w, const float* __restrict__ ln1b,
    _Float16* __restrict__ hsln,
    const float* __restrict__ xin, const float* __restrict__ ln2w, const float* __restrict__ ln2b,
    _Float16* __restrict__ kvln,
    const int* __restrict__ msk, int* __restrict__ work, int* __restrict__ cnt) {
  __shared__ float tbuf[64][65];
  int bid = blockIdx.x;
  if (bid < 256) {
    transpose_dev<1024, 1024>(Wq, WqT, bid, tbuf);
  } else if (bid < 320) {
    transpose_dev<256, 1024>(Wk, WkT, bid - 256, tbuf);
  } else if (bid < 384) {
    transpose_dev<256, 1024>(Wv, WvT, bid - 320, tbuf);
  } else if (bid < 4480) {
    ln1024_dev(hs, ln1w, ln1b, hsln, bid - 384, (float*)tbuf);
  } else if (bid < 8576) {
    ln256_dev(xin, ln2w, ln2b, kvln, bid - 4480);
  } else {
    // build LPT-sorted work list: 1024 items = (bh, qt, half), batches sorted by
    // ntiles desc; item position p has p%8 == h -> XCD locality preserved.
    // Also zero the 512 merge counters.
    int* wbuf = (int*)tbuf;   // [256] flags + [8] nt + [8] order
    int t = threadIdx.x;
    cnt[t] = 0;
    cnt[256 + t] = 0;
    int b = t >> 5, tile = t & 31;
    wbuf[t] = (msk[b * kMK + tile * 64] != 0) ? 1 : 0;
    __syncthreads();
    if (t < 8) {
      int s = 0;
      for (int i = 0; i < 32; ++i) s += wbuf[t * 32 + i];
      wbuf[256 + t] = s;
    }
    __syncthreads();
    if (t == 0) {
      int ord[8];
      for (int i = 0; i < 8; ++i) ord[i] = i;
      for (int i = 1; i < 8; ++i) {
        int o = ord[i], j = i;
        while (j > 0 && wbuf[256 + ord[j - 1]] < wbuf[256 + o]) { ord[j] = ord[j - 1]; --j; }
        ord[j] = o;
      }
      for (int i = 0; i < 8; ++i) wbuf[264 + i] = ord[i];
    }
    __syncthreads();
#pragma unroll
    for (int k = 0; k < 4; ++k) {
      int p = t + k * 256;
      int s = p >> 7, h = p & 7, qh = (p >> 3) & 15;
      int qt = qh >> 1, half = qh & 1;
      int bb = wbuf[264 + s];
      work[p] = (bb * 8 + h) | (qt << 6) | (half << 9);
    }
  }
}

// ================= unified projection GEMM =================
// C[M][N] = A[M][K] * Bt[N][K]^T + bias, 128x128 tile, BK=64, 4 waves (2x2),
// 2-phase pipeline with double-buffered LDS.
// MMODE: 0 = none, 1 = skip tile if msk[mt*128]==0, 2 = skip tile if msk[nt*128]==0.
template<int M, int N, int K, bool BIAS_ROW, int MMODE>
DI void gemm_dev(const _Float16* __restrict__ A, const _Float16* __restrict__ Bt,
                 const float* __restrict__ bias, const int* __restrict__ msk,
                 _Float16* __restrict__ C, int bid,
                 _Float16 (*As)[128 * 64], _Float16 (*Bs)[128 * 64]) {
  int tid = threadIdx.x, lane = tid & 63;
  int w = tid >> 6, wr = w >> 1, wc = w & 1;
  constexpr int NT = N / 128;
  constexpr int KT = K / 64;
  int mt = bid / NT, nt = bid % NT;
  if constexpr (MMODE == 1) { if (msk[mt * 128] == 0) return; }
  if constexpr (MMODE == 2) { if (msk[nt * 128] == 0) return; }
  const int l15 = lane & 15, l4 = lane >> 4;

  f32x4 acc[4][4] = {};

  const int rS = tid >> 3;   // staging row (0..31) per 4KB call
  const int cpS = tid & 7;   // staging physical chunk

  auto stage = [&](int kt, int bufi) {
#pragma unroll
    for (int j = 0; j < 4; ++j) {
      int rr = rS + j * 32;
      int cg = cpS ^ (rr & 7);
      gload16(A  + ((size_t)(mt * 128 + rr) * K + kt * 64 + cg * 8),
              (char*)As[bufi] + j * 4096 + tid * 16);
      gload16(Bt + ((size_t)(nt * 128 + rr) * K + kt * 64 + cg * 8),
              (char*)Bs[bufi] + j * 4096 + tid * 16);
    }
  };

  stage(0, 0);
  __syncthreads();

  for (int kt = 0; kt < KT; ++kt) {
    int cur = kt & 1;
    if (kt + 1 < KT) stage(kt + 1, cur ^ 1);
#pragma unroll
    for (int ss = 0; ss < 2; ++ss) {
      f16x8 a[4], b[4];
#pragma unroll
      for (int m = 0; m < 4; ++m) {
        int ra = wr * 64 + m * 16 + l15;
        int cl = ss * 4 + l4;
        a[m] = *(const f16x8*)((const char*)As[cur] + ra * 128 + ((cl ^ (ra & 7)) << 4));
        int rb = wc * 64 + m * 16 + l15;
        b[m] = *(const f16x8*)((const char*)Bs[cur] + rb * 128 + ((cl ^ (rb & 7)) << 4));
      }
#pragma unroll
      for (int m = 0; m < 4; ++m)
#pragma unroll
        for (int n = 0; n < 4; ++n)
          acc[m][n] = mfma16(a[m], b[n], acc[m][n]);
    }
    __syncthreads();
  }

#pragma unroll
  for (int m = 0; m < 4; ++m) {
#pragma unroll
    for (int n = 0; n < 4; ++n) {
      int gi0 = mt * 128 + wr * 64 + m * 16 + l4 * 4;
      int gj  = nt * 128 + wc * 64 + n * 16 + l15;
#pragma unroll
      for (int r = 0; r < 4; ++r) {
        int gi = gi0 + r;
        float v = acc[m][n][r] + (BIAS_ROW ? bias[gi] : bias[gj]);
        C[(size_t)gi * N + gj] = (_Float16)v;
      }
    }
  }
}

__global__ __launch_bounds__(256) void gemm_all(
    const _Float16* __restrict__ hsln, const _Float16* __restrict__ WqT,
    const float* __restrict__ bq, _Float16* __restrict__ qbf,
    const _Float16* __restrict__ kvln, const _Float16* __restrict__ WkT,
    const float* __restrict__ bk, _Float16* __restrict__ kbf,
    const _Float16* __restrict__ WvT, const float* __restrict__ bv,
    _Float16* __restrict__ vT, const int* __restrict__ msk) {
  __shared__ _Float16 As[2][128 * 64];
  __shared__ _Float16 Bs[2][128 * 64];
  int bid = blockIdx.x;
  if (bid < 256) {
    gemm_dev<4096, 1024, 1024, false, 0>(hsln, WqT, bq, nullptr, qbf, bid, As, Bs);
  } else if (bid < 1280) {
    gemm_dev<16384, 1024, 256, false, 1>(kvln, WkT, bk, msk, kbf, bid - 256, As, Bs);
  } else {
    gemm_dev<1024, 16384, 256, true, 2>(WvT, kvln, bv, msk, vT, bid - 1280, As, Bs);
  }
}

// ================= fused masked flash attention (split-K, V direct from L2) =========
// grid = 1024 work items (LPT-sorted): item = (bh, qt, half); position%8 == h -> XCD.
// LDS = K double-buffer only (32KB) -> 4 blocks/CU resident (16 waves/CU).
// V^T fragments read directly from global (L2-resident per XCD).
// Each block writes its partial (unnormalized O~ f16, m, l); the SECOND block to
// finish a (bh,qt) pair merges both partials symmetrically and writes fp32 out.
__global__ __launch_bounds__(256, 4) void attn_kernel(const _Float16* __restrict__ qm,
                                                      const _Float16* __restrict__ km,
                                                      const _Float16* __restrict__ vT,
                                                      const int* __restrict__ msk,
                                                      const int* __restrict__ work,
                                                      _Float16* __restrict__ pO,
                                                      float* __restrict__ pML,
                                                      int* __restrict__ cnt,
                                                      float* __restrict__ out) {
  __shared__ _Float16 Ks[2][64 * 128];    // [key][d]   rows 256B, 16 chunks
  __shared__ int flag;

  int tid = threadIdx.x, lane = tid & 63, w = tid >> 6;
  int v = work[blockIdx.x];
  int bh = v & 63, qt = (v >> 6) & 7, half = (v >> 9) & 1;
  int h = bh & 7, b = bh >> 3;
  const int l15 = lane & 15, l4 = lane >> 4;

  // prefix mask: number of valid 64-key tiles + exact length within last tile
  int vld = (lane < 32) ? msk[b * kMK + lane * 64] : 0;
  int ntiles = __popcll(__ballot(vld != 0));
  int lv = msk[b * kMK + (ntiles - 1) * 64 + lane];
  int lastlen = __popcll(__ballot(lv != 0));

  int h1 = (ntiles + 1) >> 1;
  int t0 = half ? h1 : 0;
  int t1 = half ? ntiles : h1;

  // Q fragments (B-operand): lane holds Q[q=w*16+l15][d = kc*32 + l4*8 + :8]
  f16x8 qf[4];
#pragma unroll
  for (int kc = 0; kc < 4; ++kc)
    qf[kc] = *(const f16x8*)(qm +
        (size_t)(b * kMQ + qt * 64 + w * 16 + l15) * kQKC +
        h * 128 + kc * 32 + l4 * 8);

  f32x4 o[8] = {};                 // O~^T: lane holds O[dv=n*16+l4*4+r][q=l15]
  float rm = -1e30f, rl = 0.0f;

  const float sl2 = 0.08838834764831845f * 1.4426950408889634f;  // scale * log2(e)

  const int rK = tid >> 4, cpK = tid & 15;   // K staging: 16 rows/call, 16 chunks/row

  auto stage = [&](int kt, int bufi) {
#pragma unroll
    for (int j = 0; j < 4; ++j) {
      int rr = rK + j * 16;
      int cg = cpK ^ (rr & 7);
      gload16(km + (size_t)(b * kMK + kt * 64 + rr) * kQKC + h * 128 + cg * 8,
              (char*)Ks[bufi] + j * 4096 + tid * 16);
    }
  };

  const _Float16* vbase = vT + (size_t)h * 128 * (kB * kMK) + (size_t)b * kMK;

  stage(t0, 0);
  __syncthreads();

  for (int kt = t0; kt < t1; ++kt) {
    int cur = (kt - t0) & 1;
    if (kt + 1 < t1) stage(kt + 1, cur ^ 1);

    // S^T = mfma(K, Q): sc[kf] holds S[key=kf*16+l4*4+r][q=l15]
    f32x4 sc[4] = {};
    __builtin_amdgcn_s_setprio(1);
#pragma unroll
    for (int kc = 0; kc < 4; ++kc) {
      f16x8 kb[4];
#pragma unroll
      for (int kf = 0; kf < 4; ++kf) {
        int rr = kf * 16 + l15;
        int cl = kc * 4 + l4;
        kb[kf] = *(const f16x8*)((const char*)Ks[cur] + rr * 256 + ((cl ^ (rr & 7)) << 4));
      }
#pragma unroll
      for (int kf = 0; kf < 4; ++kf)
        sc[kf] = mfma16(kb[kf], qf[kc], sc[kf]);
    }
    __builtin_amdgcn_s_setprio(0);

    // tail mask on the final (global) tile
    if (kt == ntiles - 1) {
#pragma unroll
      for (int kf = 0; kf < 4; ++kf)
#pragma unroll
        for (int r = 0; r < 4; ++r)
          if (kf * 16 + l4 * 4 + r >= lastlen) sc[kf][r] = -3e38f;
    }

    // lane-parallel online softmax (q = l15; keys split across l4 groups)
    float mx = sc[0][0];
#pragma unroll
    for (int kf = 0; kf < 4; ++kf)
#pragma unroll
      for (int r = 0; r < 4; ++r) mx = fmaxf(mx, sc[kf][r]);
    mx = fmaxf(mx, __shfl_xor(mx, 16));
    mx = fmaxf(mx, __shfl_xor(mx, 32));
    float al = 1.0f;
    if (__any(mx > rm)) {
      float nm = fmaxf(rm, mx);
      al = __builtin_amdgcn_exp2f((rm - nm) * sl2);
      rm = nm;
#pragma unroll
      for (int n = 0; n < 8; ++n)
#pragma unroll
        for (int r = 0; r < 4; ++r) o[n][r] *= al;
    }
    float nms = rm * sl2;
    float ts = 0.0f;
#pragma unroll
    for (int kf = 0; kf < 4; ++kf)
#pragma unroll
      for (int r = 0; r < 4; ++r) {
        float p = __builtin_amdgcn_exp2f(sc[kf][r] * sl2 - nms);
        sc[kf][r] = p;
        ts += p;
      }
    ts += __shfl_xor(ts, 16);
    ts += __shfl_xor(ts, 32);
    rl = rl * al + ts;

    // P fragments for PV (B-operand of 16x16x16): lane holds P[q=l15][k=l4*4+:4]
    f16x4 pb[4];
#pragma unroll
    for (int kf = 0; kf < 4; ++kf)
#pragma unroll
      for (int r = 0; r < 4; ++r) pb[kf][r] = (_Float16)sc[kf][r];

    // O~^T += V^T P : A-operand = V^T[dv=n*16+l15][key=kf*16+l4*4+:4], direct from L2
    __builtin_amdgcn_s_setprio(1);
#pragma unroll
    for (int n = 0; n < 8; ++n) {
      const _Float16* vrow = vbase + (size_t)(n * 16 + l15) * (kB * kMK) + kt * 64 + l4 * 4;
#pragma unroll
      for (int kf = 0; kf < 4; ++kf) {
        f16x4 vb = *(const f16x4*)(vrow + kf * 16);
        o[n] = mfma16k16(vb, pb[kf], o[n]);
      }
    }
    __builtin_amdgcn_s_setprio(0);
    __syncthreads();
  }

  // epilogue: write unnormalized partial O~ (f16) and per-row (m, l)
  int item = bh * 16 + qt * 2 + half;
  _Float16* po = pO + (size_t)item * 8192;   // [64 q][128 dv]
  int qr = w * 16 + l15;
#pragma unroll
  for (int n = 0; n < 8; ++n) {
    f16x4 st;
#pragma unroll
    for (int r = 0; r < 4; ++r) st[r] = (_Float16)o[n][r];
    *(f16x4*)(po + qr * 128 + n * 16 + l4 * 4) = st;
  }
  if (l4 == 0) {
    pML[(item * 64 + qr) * 2 + 0] = rm;
    pML[(item * 64 + qr) * 2 + 1] = rl;
  }

  // last-done block merges the two halves (symmetric -> deterministic values)
  __threadfence();
  if (tid == 0) flag = atomicAdd(&cnt[bh * 8 + qt], 1);
  __syncthreads();
  if (flag != 1) return;
  __threadfence();

  int i1 = bh * 16 + qt * 2, i2 = i1 + 1;
  int q = tid >> 2, c = tid & 3;
  float m1 = pML[(i1 * 64 + q) * 2 + 0], l1 = pML[(i1 * 64 + q) * 2 + 1];
  float m2 = pML[(i2 * 64 + q) * 2 + 0], l2 = pML[(i2 * 64 + q) * 2 + 1];
  float m = fmaxf(m1, m2);
  float w1 = __builtin_amdgcn_exp2f((m1 - m) * sl2);
  float w2 = __builtin_amdgcn_exp2f((m2 - m) * sl2);
  float inv = 1.0f / (l1 * w1 + l2 * w2);
  w1 *= inv; w2 *= inv;

  const _Float16* p1 = pO + (size_t)i1 * 8192 + q * 128;
  const _Float16* p2 = pO + (size_t)i2 * 8192 + q * 128;
  float* orow = out + ((size_t)b * kMQ + qt * 64 + q) * kVC + h * 128;
#pragma unroll
  for (int j = 0; j < 4; ++j) {
    int col = c * 32 + j * 8;
    f16x8 a = *(const f16x8*)(p1 + col);
    f16x8 bb2 = *(const f16x8*)(p2 + col);
    f32x4 o0, o1;
#pragma unroll
    for (int r = 0; r < 4; ++r) {
      o0[r] = (float)a[r] * w1 + (float)bb2[r] * w2;
      o1[r] = (float)a[4 + r] * w1 + (float)bb2[4 + r] * w2;
    }
    *(f32x4*)(orow + col) = o0;
    *(f32x4*)(orow + col + 4) = o1;
  }
}

}  // namespace

extern "C" void kernel_launch(void* const* d_in, const int* in_sizes, int n_in,
                              void* d_out, int out_size, void* d_ws, size_t ws_size,
                              hipStream_t stream) {
  (void)in_sizes; (void)n_in; (void)out_size; (void)ws_size;
  const float* hs   = (const float*)d_in[0];
  const float* xin  = (const float*)d_in[1];
  const int*   msk  = (const int*)d_in[2];
  const float* ln1w = (const float*)d_in[3];
  const float* ln1b = (const float*)d_in[4];
  const float* ln2w = (const float*)d_in[5];
  const float* ln2b = (const float*)d_in[6];
  const float* Wq   = (const float*)d_in[7];
  const float* bq   = (const float*)d_in[8];
  const float* Wk   = (const float*)d_in[9];
  const float* bk   = (const float*)d_in[10];
  const float* Wv   = (const float*)d_in[11];
  const float* bv   = (const float*)d_in[12];
  float* out = (float*)d_out;

  char* ws = (char*)d_ws;
  _Float16* qbf  = (_Float16*)(ws + 0);          //  8,388,608 B [4096][1024]
  _Float16* kbf  = (_Float16*)(ws + 8388608);    // 33,554,432 B [16384][1024]
  _Float16* vT   = (_Float16*)(ws + 41943040);   // 33,554,432 B [1024][16384]
  _Float16* hsln = (_Float16*)(ws + 75497472);   //  8,388,608 B
  _Float16* kvln = (_Float16*)(ws + 83886080);   //  8,388,608 B
  _Float16* WqT  = (_Float16*)(ws + 92274688);   //  2,097,152 B [1024][1024]
  _Float16* WkT  = (_Float16*)(ws + 94371840);   //    524,288 B [1024][256]
  _Float16* WvT  = (_Float16*)(ws + 94896128);   //    524,288 B [1024][256]
  int*      work = (int*)(ws + 95420416);        //      4,096 B [1024]
  int*      cnt  = (int*)(ws + 95424512);        //      2,048 B [512]
  // attn-phase overlays (regions dead after gemm_all):
  _Float16* pO   = hsln;                         // 16,777,216 B [1024][64][128] f16
  float*    pML  = (float*)WqT;                  //    524,288 B [1024][64][2] f32
  // total 95,426,560 B

  prep_all<<<8577, 256, 0, stream>>>(Wq, Wk, Wv, WqT, WkT, WvT,
                                     hs, ln1w, ln1b, hsln,
                                     xin, ln2w, ln2b, kvln,
                                     msk, work, cnt);
  gemm_all<<<2304, 256, 0, stream>>>(hsln, WqT, bq, qbf,
                                     kvln, WkT, bk, kbf,
                                     WvT, bv, vT, msk);
  attn_kernel<<<1024, 256, 0, stream>>>(qbf, kbf, vT, msk, work, pO, pML, cnt, out);
}

// Round 9
// 305.418 us; speedup vs baseline: 1.2848x; 1.2848x over previous
//
#include <hip/hip_runtime.h>

#define DI __device__ __forceinline__

typedef _Float16 f16x8 __attribute__((ext_vector_type(8)));
typedef _Float16 f16x4 __attribute__((ext_vector_type(4)));
typedef float    f32x4 __attribute__((ext_vector_type(4)));

namespace {

constexpr int kB  = 8;
constexpr int kMQ = 512;
constexpr int kMK = 2048;
constexpr int kQKC = 1024;   // = H*DQ
constexpr int kVC  = 1024;   // = H*DV

DI void gload16(const void* g, void* l) {
  __builtin_amdgcn_global_load_lds(
      (const __attribute__((address_space(1))) void*)g,
      (__attribute__((address_space(3))) void*)l, 16, 0, 0);
}

DI f32x4 mfma16(f16x8 a, f16x8 b, f32x4 c) {
  return __builtin_amdgcn_mfma_f32_16x16x32_f16(a, b, c, 0, 0, 0);
}

DI f32x4 mfma16k16(f16x4 a, f16x4 b, f32x4 c) {
  return __builtin_amdgcn_mfma_f32_16x16x16f16(a, b, c, 0, 0, 0);
}

// ================= unified prep: 3 weight transposes + 2 LayerNorms + worklist =====
template<int K, int N>
DI void transpose_dev(const float* __restrict__ W, _Float16* __restrict__ WT,
                      int bid, float (*t)[65]) {
  int nt = bid % (N / 64), kt = bid / (N / 64);
  int k0 = kt * 64, n0 = nt * 64;
  int tid = threadIdx.x;
#pragma unroll
  for (int j = 0; j < 16; ++j) {
    int e = tid + j * 256;
    int r = e >> 6, c = e & 63;
    t[r][c] = W[(size_t)(k0 + r) * N + n0 + c];
  }
  __syncthreads();
#pragma unroll
  for (int j = 0; j < 16; ++j) {
    int e = tid + j * 256;
    int r = e >> 6, c = e & 63;
    WT[(size_t)(n0 + r) * K + k0 + c] = (_Float16)t[c][r];
  }
}

DI void ln1024_dev(const float* __restrict__ x, const float* __restrict__ w,
                   const float* __restrict__ bb, _Float16* __restrict__ y,
                   int row, float* red) {
  int tid = threadIdx.x;
  const float4* xr = (const float4*)(x + (size_t)row * 1024);
  float4 v = xr[tid];
  float s = v.x + v.y + v.z + v.w;
  float q = v.x * v.x + v.y * v.y + v.z * v.z + v.w * v.w;
#pragma unroll
  for (int m = 32; m; m >>= 1) { s += __shfl_xor(s, m); q += __shfl_xor(q, m); }
  if ((tid & 63) == 0) { red[tid >> 6] = s; red[4 + (tid >> 6)] = q; }
  __syncthreads();
  s = red[0] + red[1] + red[2] + red[3];
  q = red[4] + red[5] + red[6] + red[7];
  float mean = s * (1.0f / 1024.0f);
  float var = q * (1.0f / 1024.0f) - mean * mean;
  float inv = rsqrtf(var + 1e-5f);
  f16x4 o;
  const float* wp = w + tid * 4;
  const float* bp = bb + tid * 4;
  o[0] = (_Float16)((v.x - mean) * inv * wp[0] + bp[0]);
  o[1] = (_Float16)((v.y - mean) * inv * wp[1] + bp[1]);
  o[2] = (_Float16)((v.z - mean) * inv * wp[2] + bp[2]);
  o[3] = (_Float16)((v.w - mean) * inv * wp[3] + bp[3]);
  *(f16x4*)(y + (size_t)row * 1024 + tid * 4) = o;
}

DI void ln256_dev(const float* __restrict__ x, const float* __restrict__ w,
                  const float* __restrict__ bb, _Float16* __restrict__ y, int bid) {
  int tid = threadIdx.x;
  int lane = tid & 63, wv = tid >> 6;
  size_t row = (size_t)bid * 4 + wv;
  const float4* xr = (const float4*)(x + row * 256);
  float4 v = xr[lane];
  float s = v.x + v.y + v.z + v.w;
  float q = v.x * v.x + v.y * v.y + v.z * v.z + v.w * v.w;
#pragma unroll
  for (int m = 32; m; m >>= 1) { s += __shfl_xor(s, m); q += __shfl_xor(q, m); }
  float mean = s * (1.0f / 256.0f);
  float var = q * (1.0f / 256.0f) - mean * mean;
  float inv = rsqrtf(var + 1e-5f);
  f16x4 o;
  const float* wp = w + lane * 4;
  const float* bp = bb + lane * 4;
  o[0] = (_Float16)((v.x - mean) * inv * wp[0] + bp[0]);
  o[1] = (_Float16)((v.y - mean) * inv * wp[1] + bp[1]);
  o[2] = (_Float16)((v.z - mean) * inv * wp[2] + bp[2]);
  o[3] = (_Float16)((v.w - mean) * inv * wp[3] + bp[3]);
  *(f16x4*)(y + row * 256 + lane * 4) = o;
}

__global__ __launch_bounds__(256) void prep_all(
    const float* __restrict__ Wq, const float* __restrict__ Wk, const float* __restrict__ Wv,
    _Float16* __restrict__ WqT, _Float16* __restrict__ WkT, _Float16* __restrict__ WvT,
    const float* __restrict__ hs, const float* __restrict__ ln1w, const float* __restrict__ ln1b,
    _Float16* __restrict__ hsln,
    const float* __restrict__ xin, const float* __restrict__ ln2w, const float* __restrict__ ln2b,
    _Float16* __restrict__ kvln,
    const int* __restrict__ msk, int* __restrict__ work, int* __restrict__ cnt) {
  __shared__ float tbuf[64][65];
  int bid = blockIdx.x;
  if (bid < 256) {
    transpose_dev<1024, 1024>(Wq, WqT, bid, tbuf);
  } else if (bid < 320) {
    transpose_dev<256, 1024>(Wk, WkT, bid - 256, tbuf);
  } else if (bid < 384) {
    transpose_dev<256, 1024>(Wv, WvT, bid - 320, tbuf);
  } else if (bid < 4480) {
    ln1024_dev(hs, ln1w, ln1b, hsln, bid - 384, (float*)tbuf);
  } else if (bid < 8576) {
    ln256_dev(xin, ln2w, ln2b, kvln, bid - 4480);
  } else {
    // build LPT-sorted work list: 1024 items = (bh, qt, half), batches sorted by
    // ntiles desc; item position p has p%8 == h -> XCD locality preserved.
    // Also zero the 512 merge counters.
    int* wbuf = (int*)tbuf;   // [256] flags + [8] nt + [8] order
    int t = threadIdx.x;
    cnt[t] = 0;
    cnt[256 + t] = 0;
    int b = t >> 5, tile = t & 31;
    wbuf[t] = (msk[b * kMK + tile * 64] != 0) ? 1 : 0;
    __syncthreads();
    if (t < 8) {
      int s = 0;
      for (int i = 0; i < 32; ++i) s += wbuf[t * 32 + i];
      wbuf[256 + t] = s;
    }
    __syncthreads();
    if (t == 0) {
      int ord[8];
      for (int i = 0; i < 8; ++i) ord[i] = i;
      for (int i = 1; i < 8; ++i) {
        int o = ord[i], j = i;
        while (j > 0 && wbuf[256 + ord[j - 1]] < wbuf[256 + o]) { ord[j] = ord[j - 1]; --j; }
        ord[j] = o;
      }
      for (int i = 0; i < 8; ++i) wbuf[264 + i] = ord[i];
    }
    __syncthreads();
#pragma unroll
    for (int k = 0; k < 4; ++k) {
      int p = t + k * 256;
      int s = p >> 7, h = p & 7, qh = (p >> 3) & 15;
      int qt = qh >> 1, half = qh & 1;
      int bb = wbuf[264 + s];
      work[p] = (bb * 8 + h) | (qt << 6) | (half << 9);
    }
  }
}

// ================= unified projection GEMM =================
template<int M, int N, int K, bool BIAS_ROW, int MMODE>
DI void gemm_dev(const _Float16* __restrict__ A, const _Float16* __restrict__ Bt,
                 const float* __restrict__ bias, const int* __restrict__ msk,
                 _Float16* __restrict__ C, int bid,
                 _Float16 (*As)[128 * 64], _Float16 (*Bs)[128 * 64]) {
  int tid = threadIdx.x, lane = tid & 63;
  int w = tid >> 6, wr = w >> 1, wc = w & 1;
  constexpr int NT = N / 128;
  constexpr int KT = K / 64;
  int mt = bid / NT, nt = bid % NT;
  if constexpr (MMODE == 1) { if (msk[mt * 128] == 0) return; }
  if constexpr (MMODE == 2) { if (msk[nt * 128] == 0) return; }
  const int l15 = lane & 15, l4 = lane >> 4;

  f32x4 acc[4][4] = {};

  const int rS = tid >> 3;   // staging row (0..31) per 4KB call
  const int cpS = tid & 7;   // staging physical chunk

  auto stage = [&](int kt, int bufi) {
#pragma unroll
    for (int j = 0; j < 4; ++j) {
      int rr = rS + j * 32;
      int cg = cpS ^ (rr & 7);
      gload16(A  + ((size_t)(mt * 128 + rr) * K + kt * 64 + cg * 8),
              (char*)As[bufi] + j * 4096 + tid * 16);
      gload16(Bt + ((size_t)(nt * 128 + rr) * K + kt * 64 + cg * 8),
              (char*)Bs[bufi] + j * 4096 + tid * 16);
    }
  };

  stage(0, 0);
  __syncthreads();

  for (int kt = 0; kt < KT; ++kt) {
    int cur = kt & 1;
    if (kt + 1 < KT) stage(kt + 1, cur ^ 1);
#pragma unroll
    for (int ss = 0; ss < 2; ++ss) {
      f16x8 a[4], b[4];
#pragma unroll
      for (int m = 0; m < 4; ++m) {
        int ra = wr * 64 + m * 16 + l15;
        int cl = ss * 4 + l4;
        a[m] = *(const f16x8*)((const char*)As[cur] + ra * 128 + ((cl ^ (ra & 7)) << 4));
        int rb = wc * 64 + m * 16 + l15;
        b[m] = *(const f16x8*)((const char*)Bs[cur] + rb * 128 + ((cl ^ (rb & 7)) << 4));
      }
#pragma unroll
      for (int m = 0; m < 4; ++m)
#pragma unroll
        for (int n = 0; n < 4; ++n)
          acc[m][n] = mfma16(a[m], b[n], acc[m][n]);
    }
    __syncthreads();
  }

#pragma unroll
  for (int m = 0; m < 4; ++m) {
#pragma unroll
    for (int n = 0; n < 4; ++n) {
      int gi0 = mt * 128 + wr * 64 + m * 16 + l4 * 4;
      int gj  = nt * 128 + wc * 64 + n * 16 + l15;
#pragma unroll
      for (int r = 0; r < 4; ++r) {
        int gi = gi0 + r;
        float v = acc[m][n][r] + (BIAS_ROW ? bias[gi] : bias[gj]);
        C[(size_t)gi * N + gj] = (_Float16)v;
      }
    }
  }
}

__global__ __launch_bounds__(256) void gemm_all(
    const _Float16* __restrict__ hsln, const _Float16* __restrict__ WqT,
    const float* __restrict__ bq, _Float16* __restrict__ qbf,
    const _Float16* __restrict__ kvln, const _Float16* __restrict__ WkT,
    const float* __restrict__ bk, _Float16* __restrict__ kbf,
    const _Float16* __restrict__ WvT, const float* __restrict__ bv,
    _Float16* __restrict__ vT, const int* __restrict__ msk) {
  __shared__ _Float16 As[2][128 * 64];
  __shared__ _Float16 Bs[2][128 * 64];
  int bid = blockIdx.x;
  if (bid < 256) {
    gemm_dev<4096, 1024, 1024, false, 0>(hsln, WqT, bq, nullptr, qbf, bid, As, Bs);
  } else if (bid < 1280) {
    gemm_dev<16384, 1024, 256, false, 1>(kvln, WkT, bk, msk, kbf, bid - 256, As, Bs);
  } else {
    gemm_dev<1024, 16384, 256, true, 2>(WvT, kvln, bv, msk, vT, bid - 1280, As, Bs);
  }
}

// ================= fused masked flash attention (split-K + fused merge) =============
// grid = 1024 work items (LPT-sorted): item = (bh, qt, half); position%8 == h -> XCD.
// K and V^T double-buffered in LDS (64KB, 2 blocks/CU) — the proven round-7 core.
// Each block writes its partial (unnormalized O~ f16, m, l); the SECOND block to
// finish a (bh,qt) pair merges both partials symmetrically and writes fp32 out.
__global__ __launch_bounds__(256, 2) void attn_kernel(const _Float16* __restrict__ qm,
                                                      const _Float16* __restrict__ km,
                                                      const _Float16* __restrict__ vT,
                                                      const int* __restrict__ msk,
                                                      const int* __restrict__ work,
                                                      _Float16* __restrict__ pO,
                                                      float* __restrict__ pML,
                                                      int* __restrict__ cnt,
                                                      float* __restrict__ out) {
  __shared__ _Float16 Ks[2][64 * 128];    // [key][d]   rows 256B, 16 chunks
  __shared__ _Float16 Vst[2][128 * 64];   // [dv][key]  rows 128B, 8 chunks
  __shared__ int flag;

  int tid = threadIdx.x, lane = tid & 63, w = tid >> 6;
  int v = work[blockIdx.x];
  int bh = v & 63, qt = (v >> 6) & 7, half = (v >> 9) & 1;
  int h = bh & 7, b = bh >> 3;
  const int l15 = lane & 15, l4 = lane >> 4;

  // prefix mask: number of valid 64-key tiles + exact length within last tile
  int vld = (lane < 32) ? msk[b * kMK + lane * 64] : 0;
  int ntiles = __popcll(__ballot(vld != 0));
  int lv = msk[b * kMK + (ntiles - 1) * 64 + lane];
  int lastlen = __popcll(__ballot(lv != 0));

  int h1 = (ntiles + 1) >> 1;
  int t0 = half ? h1 : 0;
  int t1 = half ? ntiles : h1;

  // Q fragments (B-operand): lane holds Q[q=w*16+l15][d = kc*32 + l4*8 + :8]
  f16x8 qf[4];
#pragma unroll
  for (int kc = 0; kc < 4; ++kc)
    qf[kc] = *(const f16x8*)(qm +
        (size_t)(b * kMQ + qt * 64 + w * 16 + l15) * kQKC +
        h * 128 + kc * 32 + l4 * 8);

  f32x4 o[8] = {};                 // O~^T: lane holds O[dv=n*16+l4*4+r][q=l15]
  float rm = -1e30f, rl = 0.0f;

  const float sl2 = 0.08838834764831845f * 1.4426950408889634f;  // scale * log2(e)

  const int rK = tid >> 4, cpK = tid & 15;   // K staging: 16 rows/call, 16 chunks/row
  const int rV = tid >> 3, cpV = tid & 7;    // V staging: 32 rows/call, 8 chunks/row

  auto stage = [&](int kt, int bufi) {
#pragma unroll
    for (int j = 0; j < 4; ++j) {
      int rr = rK + j * 16;
      int cg = cpK ^ (rr & 7);
      gload16(km + (size_t)(b * kMK + kt * 64 + rr) * kQKC + h * 128 + cg * 8,
              (char*)Ks[bufi] + j * 4096 + tid * 16);
    }
#pragma unroll
    for (int j = 0; j < 4; ++j) {
      int dv = rV + j * 32;
      int cg = cpV ^ (dv & 7);
      gload16(vT + (size_t)(h * 128 + dv) * (kB * kMK) + (size_t)b * kMK + kt * 64 + cg * 8,
              (char*)Vst[bufi] + j * 4096 + tid * 16);
    }
  };

  stage(t0, 0);
  __syncthreads();

  for (int kt = t0; kt < t1; ++kt) {
    int cur = (kt - t0) & 1;
    if (kt + 1 < t1) stage(kt + 1, cur ^ 1);

    // S^T = mfma(K, Q): sc[kf] holds S[key=kf*16+l4*4+r][q=l15]
    f32x4 sc[4] = {};
    __builtin_amdgcn_s_setprio(1);
#pragma unroll
    for (int kc = 0; kc < 4; ++kc) {
      f16x8 kb[4];
#pragma unroll
      for (int kf = 0; kf < 4; ++kf) {
        int rr = kf * 16 + l15;
        int cl = kc * 4 + l4;
        kb[kf] = *(const f16x8*)((const char*)Ks[cur] + rr * 256 + ((cl ^ (rr & 7)) << 4));
      }
#pragma unroll
      for (int kf = 0; kf < 4; ++kf)
        sc[kf] = mfma16(kb[kf], qf[kc], sc[kf]);
    }
    __builtin_amdgcn_s_setprio(0);

    // tail mask on the final (global) tile
    if (kt == ntiles - 1) {
#pragma unroll
      for (int kf = 0; kf < 4; ++kf)
#pragma unroll
        for (int r = 0; r < 4; ++r)
          if (kf * 16 + l4 * 4 + r >= lastlen) sc[kf][r] = -3e38f;
    }

    // lane-parallel online softmax (q = l15; keys split across l4 groups)
    float mx = sc[0][0];
#pragma unroll
    for (int kf = 0; kf < 4; ++kf)
#pragma unroll
      for (int r = 0; r < 4; ++r) mx = fmaxf(mx, sc[kf][r]);
    mx = fmaxf(mx, __shfl_xor(mx, 16));
    mx = fmaxf(mx, __shfl_xor(mx, 32));
    float al = 1.0f;
    if (__any(mx > rm)) {
      float nm = fmaxf(rm, mx);
      al = __builtin_amdgcn_exp2f((rm - nm) * sl2);
      rm = nm;
#pragma unroll
      for (int n = 0; n < 8; ++n)
#pragma unroll
        for (int r = 0; r < 4; ++r) o[n][r] *= al;
    }
    float nms = rm * sl2;
    float ts = 0.0f;
#pragma unroll
    for (int kf = 0; kf < 4; ++kf)
#pragma unroll
      for (int r = 0; r < 4; ++r) {
        float p = __builtin_amdgcn_exp2f(sc[kf][r] * sl2 - nms);
        sc[kf][r] = p;
        ts += p;
      }
    ts += __shfl_xor(ts, 16);
    ts += __shfl_xor(ts, 32);
    rl = rl * al + ts;

    // P fragments for PV (B-operand of 16x16x16): lane holds P[q=l15][k=l4*4+:4]
    f16x4 pb[4];
#pragma unroll
    for (int kf = 0; kf < 4; ++kf)
#pragma unroll
      for (int r = 0; r < 4; ++r) pb[kf][r] = (_Float16)sc[kf][r];

    // O~^T += V^T P : A-operand = V^T[dv=n*16+l15][key=kf*16+l4*4+:4]
    __builtin_amdgcn_s_setprio(1);
#pragma unroll
    for (int n = 0; n < 8; ++n) {
      int dv = n * 16 + l15;
#pragma unroll
      for (int kf = 0; kf < 4; ++kf) {
        int phys = (kf * 2 + (l4 >> 1)) ^ (l15 & 7);
        f16x4 vb = *(const f16x4*)((const char*)Vst[cur] +
                                   dv * 128 + (phys << 4) + (l4 & 1) * 8);
        o[n] = mfma16k16(vb, pb[kf], o[n]);
      }
    }
    __builtin_amdgcn_s_setprio(0);
    __syncthreads();
  }

  // epilogue: write unnormalized partial O~ (f16) and per-row (m, l)
  int item = bh * 16 + qt * 2 + half;
  _Float16* po = pO + (size_t)item * 8192;   // [64 q][128 dv]
  int qr = w * 16 + l15;
#pragma unroll
  for (int n = 0; n < 8; ++n) {
    f16x4 st;
#pragma unroll
    for (int r = 0; r < 4; ++r) st[r] = (_Float16)o[n][r];
    *(f16x4*)(po + qr * 128 + n * 16 + l4 * 4) = st;
  }
  if (l4 == 0) {
    pML[(item * 64 + qr) * 2 + 0] = rm;
    pML[(item * 64 + qr) * 2 + 1] = rl;
  }

  // last-done block merges the two halves (symmetric -> deterministic values)
  __threadfence();
  if (tid == 0) flag = atomicAdd(&cnt[bh * 8 + qt], 1);
  __syncthreads();
  if (flag != 1) return;
  __threadfence();

  int i1 = bh * 16 + qt * 2, i2 = i1 + 1;
  int q = tid >> 2, c = tid & 3;
  float m1 = pML[(i1 * 64 + q) * 2 + 0], l1 = pML[(i1 * 64 + q) * 2 + 1];
  float m2 = pML[(i2 * 64 + q) * 2 + 0], l2 = pML[(i2 * 64 + q) * 2 + 1];
  float m = fmaxf(m1, m2);
  float w1 = __builtin_amdgcn_exp2f((m1 - m) * sl2);
  float w2 = __builtin_amdgcn_exp2f((m2 - m) * sl2);
  float inv = 1.0f / (l1 * w1 + l2 * w2);
  w1 *= inv; w2 *= inv;

  const _Float16* p1 = pO + (size_t)i1 * 8192 + q * 128;
  const _Float16* p2 = pO + (size_t)i2 * 8192 + q * 128;
  float* orow = out + ((size_t)b * kMQ + qt * 64 + q) * kVC + h * 128;
#pragma unroll
  for (int j = 0; j < 4; ++j) {
    int col = c * 32 + j * 8;
    f16x8 a = *(const f16x8*)(p1 + col);
    f16x8 bb2 = *(const f16x8*)(p2 + col);
    f32x4 o0, o1;
#pragma unroll
    for (int r = 0; r < 4; ++r) {
      o0[r] = (float)a[r] * w1 + (float)bb2[r] * w2;
      o1[r] = (float)a[4 + r] * w1 + (float)bb2[4 + r] * w2;
    }
    *(f32x4*)(orow + col) = o0;
    *(f32x4*)(orow + col + 4) = o1;
  }
}

}  // namespace

extern "C" void kernel_launch(void* const* d_in, const int* in_sizes, int n_in,
                              void* d_out, int out_size, void* d_ws, size_t ws_size,
                              hipStream_t stream) {
  (void)in_sizes; (void)n_in; (void)out_size; (void)ws_size;
  const float* hs   = (const float*)d_in[0];
  const float* xin  = (const float*)d_in[1];
  const int*   msk  = (const int*)d_in[2];
  const float* ln1w = (const float*)d_in[3];
  const float* ln1b = (const float*)d_in[4];
  const float* ln2w = (const float*)d_in[5];
  const float* ln2b = (const float*)d_in[6];
  const float* Wq   = (const float*)d_in[7];
  const float* bq   = (const float*)d_in[8];
  const float* Wk   = (const float*)d_in[9];
  const float* bk   = (const float*)d_in[10];
  const float* Wv   = (const float*)d_in[11];
  const float* bv   = (const float*)d_in[12];
  float* out = (float*)d_out;

  char* ws = (char*)d_ws;
  _Float16* qbf  = (_Float16*)(ws + 0);          //  8,388,608 B [4096][1024]
  _Float16* kbf  = (_Float16*)(ws + 8388608);    // 33,554,432 B [16384][1024]
  _Float16* vT   = (_Float16*)(ws + 41943040);   // 33,554,432 B [1024][16384]
  _Float16* hsln = (_Float16*)(ws + 75497472);   //  8,388,608 B
  _Float16* kvln = (_Float16*)(ws + 83886080);   //  8,388,608 B
  _Float16* WqT  = (_Float16*)(ws + 92274688);   //  2,097,152 B [1024][1024]
  _Float16* WkT  = (_Float16*)(ws + 94371840);   //    524,288 B [1024][256]
  _Float16* WvT  = (_Float16*)(ws + 94896128);   //    524,288 B [1024][256]
  int*      work = (int*)(ws + 95420416);        //      4,096 B [1024]
  int*      cnt  = (int*)(ws + 95424512);        //      2,048 B [512]
  // attn-phase overlays (regions dead after gemm_all):
  _Float16* pO   = hsln;                         // 16,777,216 B [1024][64][128] f16
  float*    pML  = (float*)WqT;                  //    524,288 B [1024][64][2] f32
  // total 95,426,560 B

  prep_all<<<8577, 256, 0, stream>>>(Wq, Wk, Wv, WqT, WkT, WvT,
                                     hs, ln1w, ln1b, hsln,
                                     xin, ln2w, ln2b, kvln,
                                     msk, work, cnt);
  gemm_all<<<2304, 256, 0, stream>>>(hsln, WqT, bq, qbf,
                                     kvln, WkT, bk, kbf,
                                     WvT, bv, vT, msk);
  attn_kernel<<<1024, 256, 0, stream>>>(qbf, kbf, vT, msk, work, pO, pML, cnt, out);
}

// Round 10
// 117.485 us; speedup vs baseline: 3.3401x; 2.5996x over previous
//
#include <hip/hip_runtime.h>

#define DI __device__ __forceinline__

typedef _Float16 f16x8 __attribute__((ext_vector_type(8)));
typedef _Float16 f16x4 __attribute__((ext_vector_type(4)));
typedef float    f32x4 __attribute__((ext_vector_type(4)));

namespace {

constexpr int kB  = 8;
constexpr int kMQ = 512;
constexpr int kMK = 2048;
constexpr int kQKC = 1024;   // = H*DQ
constexpr int kVC  = 1024;   // = H*DV

DI void gload16(const void* g, void* l) {
  __builtin_amdgcn_global_load_lds(
      (const __attribute__((address_space(1))) void*)g,
      (__attribute__((address_space(3))) void*)l, 16, 0, 0);
}

DI f32x4 mfma16(f16x8 a, f16x8 b, f32x4 c) {
  return __builtin_amdgcn_mfma_f32_16x16x32_f16(a, b, c, 0, 0, 0);
}

DI f32x4 mfma16k16(f16x4 a, f16x4 b, f32x4 c) {
  return __builtin_amdgcn_mfma_f32_16x16x16f16(a, b, c, 0, 0, 0);
}

// ================= unified prep: 3 weight transposes + 2 LayerNorms =================
template<int K, int N>
DI void transpose_dev(const float* __restrict__ W, _Float16* __restrict__ WT,
                      int bid, float (*t)[65]) {
  int nt = bid % (N / 64), kt = bid / (N / 64);
  int k0 = kt * 64, n0 = nt * 64;
  int tid = threadIdx.x;
#pragma unroll
  for (int j = 0; j < 16; ++j) {
    int e = tid + j * 256;
    int r = e >> 6, c = e & 63;
    t[r][c] = W[(size_t)(k0 + r) * N + n0 + c];
  }
  __syncthreads();
#pragma unroll
  for (int j = 0; j < 16; ++j) {
    int e = tid + j * 256;
    int r = e >> 6, c = e & 63;
    WT[(size_t)(n0 + r) * K + k0 + c] = (_Float16)t[c][r];
  }
}

DI void ln1024_dev(const float* __restrict__ x, const float* __restrict__ w,
                   const float* __restrict__ bb, _Float16* __restrict__ y,
                   int row, float* red) {
  int tid = threadIdx.x;
  const float4* xr = (const float4*)(x + (size_t)row * 1024);
  float4 v = xr[tid];
  float s = v.x + v.y + v.z + v.w;
  float q = v.x * v.x + v.y * v.y + v.z * v.z + v.w * v.w;
#pragma unroll
  for (int m = 32; m; m >>= 1) { s += __shfl_xor(s, m); q += __shfl_xor(q, m); }
  if ((tid & 63) == 0) { red[tid >> 6] = s; red[4 + (tid >> 6)] = q; }
  __syncthreads();
  s = red[0] + red[1] + red[2] + red[3];
  q = red[4] + red[5] + red[6] + red[7];
  float mean = s * (1.0f / 1024.0f);
  float var = q * (1.0f / 1024.0f) - mean * mean;
  float inv = rsqrtf(var + 1e-5f);
  f16x4 o;
  const float* wp = w + tid * 4;
  const float* bp = bb + tid * 4;
  o[0] = (_Float16)((v.x - mean) * inv * wp[0] + bp[0]);
  o[1] = (_Float16)((v.y - mean) * inv * wp[1] + bp[1]);
  o[2] = (_Float16)((v.z - mean) * inv * wp[2] + bp[2]);
  o[3] = (_Float16)((v.w - mean) * inv * wp[3] + bp[3]);
  *(f16x4*)(y + (size_t)row * 1024 + tid * 4) = o;
}

DI void ln256_dev(const float* __restrict__ x, const float* __restrict__ w,
                  const float* __restrict__ bb, _Float16* __restrict__ y, int bid) {
  int tid = threadIdx.x;
  int lane = tid & 63, wv = tid >> 6;
  size_t row = (size_t)bid * 4 + wv;
  const float4* xr = (const float4*)(x + row * 256);
  float4 v = xr[lane];
  float s = v.x + v.y + v.z + v.w;
  float q = v.x * v.x + v.y * v.y + v.z * v.z + v.w * v.w;
#pragma unroll
  for (int m = 32; m; m >>= 1) { s += __shfl_xor(s, m); q += __shfl_xor(q, m); }
  float mean = s * (1.0f / 256.0f);
  float var = q * (1.0f / 256.0f) - mean * mean;
  float inv = rsqrtf(var + 1e-5f);
  f16x4 o;
  const float* wp = w + lane * 4;
  const float* bp = bb + lane * 4;
  o[0] = (_Float16)((v.x - mean) * inv * wp[0] + bp[0]);
  o[1] = (_Float16)((v.y - mean) * inv * wp[1] + bp[1]);
  o[2] = (_Float16)((v.z - mean) * inv * wp[2] + bp[2]);
  o[3] = (_Float16)((v.w - mean) * inv * wp[3] + bp[3]);
  *(f16x4*)(y + row * 256 + lane * 4) = o;
}

__global__ __launch_bounds__(256) void prep_all(
    const float* __restrict__ Wq, const float* __restrict__ Wk, const float* __restrict__ Wv,
    _Float16* __restrict__ WqT, _Float16* __restrict__ WkT, _Float16* __restrict__ WvT,
    const float* __restrict__ hs, const float* __restrict__ ln1w, const float* __restrict__ ln1b,
    _Float16* __restrict__ hsln,
    const float* __restrict__ xin, const float* __restrict__ ln2w, const float* __restrict__ ln2b,
    _Float16* __restrict__ kvln) {
  __shared__ float tbuf[64][65];
  int bid = blockIdx.x;
  if (bid < 256) {
    transpose_dev<1024, 1024>(Wq, WqT, bid, tbuf);
  } else if (bid < 320) {
    transpose_dev<256, 1024>(Wk, WkT, bid - 256, tbuf);
  } else if (bid < 384) {
    transpose_dev<256, 1024>(Wv, WvT, bid - 320, tbuf);
  } else if (bid < 4480) {
    ln1024_dev(hs, ln1w, ln1b, hsln, bid - 384, (float*)tbuf);
  } else {
    ln256_dev(xin, ln2w, ln2b, kvln, bid - 4480);
  }
}

// ================= unified projection GEMM =================
// C[M][N] = A[M][K] * Bt[N][K]^T + bias, 128x128 tile, BK=64, 4 waves (2x2),
// 2-phase pipeline with double-buffered LDS.
// MMODE: 0 = none, 1 = skip tile if msk[mt*128]==0, 2 = skip tile if msk[nt*128]==0.
// CM (column-major decode): mt = bid % MT, nt = bid / MT -> the blocks sharing one
// A row-panel sit at bid-stride MT ≡ 0 (mod 8) -> same XCD -> A re-reads are L2 hits.
// (B is small, 0.5-2 MB, L2-resident per XCD.) Use CM for q/k GEMMs; the v GEMM's
// big operand is B (kvln) whose sharers are already stride-NT -> keep row-major.
template<int M, int N, int K, bool BIAS_ROW, int MMODE, bool CM>
DI void gemm_dev(const _Float16* __restrict__ A, const _Float16* __restrict__ Bt,
                 const float* __restrict__ bias, const int* __restrict__ msk,
                 _Float16* __restrict__ C, int bid,
                 _Float16 (*As)[128 * 64], _Float16 (*Bs)[128 * 64]) {
  int tid = threadIdx.x, lane = tid & 63;
  int w = tid >> 6, wr = w >> 1, wc = w & 1;
  constexpr int NT = N / 128;
  constexpr int MT = M / 128;
  constexpr int KT = K / 64;
  int mt, nt;
  if constexpr (CM) { mt = bid % MT; nt = bid / MT; }
  else              { mt = bid / NT; nt = bid % NT; }
  if constexpr (MMODE == 1) { if (msk[mt * 128] == 0) return; }
  if constexpr (MMODE == 2) { if (msk[nt * 128] == 0) return; }
  const int l15 = lane & 15, l4 = lane >> 4;

  f32x4 acc[4][4] = {};

  const int rS = tid >> 3;   // staging row (0..31) per 4KB call
  const int cpS = tid & 7;   // staging physical chunk

  auto stage = [&](int kt, int bufi) {
#pragma unroll
    for (int j = 0; j < 4; ++j) {
      int rr = rS + j * 32;
      int cg = cpS ^ (rr & 7);
      gload16(A  + ((size_t)(mt * 128 + rr) * K + kt * 64 + cg * 8),
              (char*)As[bufi] + j * 4096 + tid * 16);
      gload16(Bt + ((size_t)(nt * 128 + rr) * K + kt * 64 + cg * 8),
              (char*)Bs[bufi] + j * 4096 + tid * 16);
    }
  };

  stage(0, 0);
  __syncthreads();

  for (int kt = 0; kt < KT; ++kt) {
    int cur = kt & 1;
    if (kt + 1 < KT) stage(kt + 1, cur ^ 1);
#pragma unroll
    for (int ss = 0; ss < 2; ++ss) {
      f16x8 a[4], b[4];
#pragma unroll
      for (int m = 0; m < 4; ++m) {
        int ra = wr * 64 + m * 16 + l15;
        int cl = ss * 4 + l4;
        a[m] = *(const f16x8*)((const char*)As[cur] + ra * 128 + ((cl ^ (ra & 7)) << 4));
        int rb = wc * 64 + m * 16 + l15;
        b[m] = *(const f16x8*)((const char*)Bs[cur] + rb * 128 + ((cl ^ (rb & 7)) << 4));
      }
#pragma unroll
      for (int m = 0; m < 4; ++m)
#pragma unroll
        for (int n = 0; n < 4; ++n)
          acc[m][n] = mfma16(a[m], b[n], acc[m][n]);
    }
    __syncthreads();
  }

#pragma unroll
  for (int m = 0; m < 4; ++m) {
#pragma unroll
    for (int n = 0; n < 4; ++n) {
      int gi0 = mt * 128 + wr * 64 + m * 16 + l4 * 4;
      int gj  = nt * 128 + wc * 64 + n * 16 + l15;
#pragma unroll
      for (int r = 0; r < 4; ++r) {
        int gi = gi0 + r;
        float v = acc[m][n][r] + (BIAS_ROW ? bias[gi] : bias[gj]);
        C[(size_t)gi * N + gj] = (_Float16)v;
      }
    }
  }
}

__global__ __launch_bounds__(256) void gemm_all(
    const _Float16* __restrict__ hsln, const _Float16* __restrict__ WqT,
    const float* __restrict__ bq, _Float16* __restrict__ qbf,
    const _Float16* __restrict__ kvln, const _Float16* __restrict__ WkT,
    const float* __restrict__ bk, _Float16* __restrict__ kbf,
    const _Float16* __restrict__ WvT, const float* __restrict__ bv,
    _Float16* __restrict__ vT, const int* __restrict__ msk) {
  __shared__ _Float16 As[2][128 * 64];
  __shared__ _Float16 Bs[2][128 * 64];
  int bid = blockIdx.x;
  if (bid < 256) {
    gemm_dev<4096, 1024, 1024, false, 0, true>(hsln, WqT, bq, nullptr, qbf, bid, As, Bs);
  } else if (bid < 1280) {
    gemm_dev<16384, 1024, 256, false, 1, true>(kvln, WkT, bk, msk, kbf, bid - 256, As, Bs);
  } else {
    gemm_dev<1024, 16384, 256, true, 2, false>(WvT, kvln, bv, msk, vT, bid - 1280, As, Bs);
  }
}

// ================= fused masked flash attention (swapped-operand form) =================
// grid = 512: bh = blockIdx%64 (XCD locality), qt = blockIdx/64.
// 256 threads = 4 waves, each wave owns 16 q rows (q = lane&15). K-tile = 64 keys.
// Swapped QK: S^T = mfma(K,Q) -> lane holds S[key=kf*16+l4*4+r][q=l15].
// Softmax lane-parallel; PV via 16x16x16 with P in registers; O^T accumulates.
// K and V^T double-buffered via global_load_lds (swizzled), 2-phase pipeline.
// Rescale of O skipped when running max unchanged (exact, T13-style guard).
__global__ __launch_bounds__(256, 2) void attn_kernel(const _Float16* __restrict__ qm,
                                                      const _Float16* __restrict__ km,
                                                      const _Float16* __restrict__ vT,
                                                      const int* __restrict__ msk,
                                                      float* __restrict__ out) {
  __shared__ _Float16 Ks[2][64 * 128];    // [key][d]   rows 256B, 16 chunks
  __shared__ _Float16 Vst[2][128 * 64];   // [dv][key]  rows 128B, 8 chunks

  int tid = threadIdx.x, lane = tid & 63, w = tid >> 6;
  int bh = blockIdx.x & 63, qt = blockIdx.x >> 6;
  int h = bh & 7, b = bh >> 3;
  const int l15 = lane & 15, l4 = lane >> 4;

  // prefix mask: number of valid 64-key tiles + exact length within last tile
  int vld = (lane < 32) ? msk[b * kMK + lane * 64] : 0;
  int ntiles = __popcll(__ballot(vld != 0));
  int lv = msk[b * kMK + (ntiles - 1) * 64 + lane];
  int lastlen = __popcll(__ballot(lv != 0));

  // Q fragments (B-operand): lane holds Q[q=w*16+l15][d = kc*32 + l4*8 + :8]
  f16x8 qf[4];
#pragma unroll
  for (int kc = 0; kc < 4; ++kc)
    qf[kc] = *(const f16x8*)(qm +
        (size_t)(b * kMQ + qt * 64 + w * 16 + l15) * kQKC +
        h * 128 + kc * 32 + l4 * 8);

  f32x4 o[8] = {};                 // O^T: lane holds O[dv=n*16+l4*4+r][q=l15]
  float rm = -1e30f, rl = 0.0f;

  const float sl2 = 0.08838834764831845f * 1.4426950408889634f;  // scale * log2(e)

  const int rK = tid >> 4, cpK = tid & 15;   // K staging: 16 rows/call, 16 chunks/row
  const int rV = tid >> 3, cpV = tid & 7;    // V staging: 32 rows/call, 8 chunks/row

  auto stage = [&](int kt, int bufi) {
#pragma unroll
    for (int j = 0; j < 4; ++j) {
      int rr = rK + j * 16;
      int cg = cpK ^ (rr & 7);
      gload16(km + (size_t)(b * kMK + kt * 64 + rr) * kQKC + h * 128 + cg * 8,
              (char*)Ks[bufi] + j * 4096 + tid * 16);
    }
#pragma unroll
    for (int j = 0; j < 4; ++j) {
      int dv = rV + j * 32;
      int cg = cpV ^ (dv & 7);
      gload16(vT + (size_t)(h * 128 + dv) * (kB * kMK) + (size_t)b * kMK + kt * 64 + cg * 8,
              (char*)Vst[bufi] + j * 4096 + tid * 16);
    }
  };

  stage(0, 0);
  __syncthreads();

  for (int kt = 0; kt < ntiles; ++kt) {
    int cur = kt & 1;
    if (kt + 1 < ntiles) stage(kt + 1, cur ^ 1);

    // S^T = mfma(K, Q): sc[kf] holds S[key=kf*16+l4*4+r][q=l15]
    f32x4 sc[4] = {};
    __builtin_amdgcn_s_setprio(1);
#pragma unroll
    for (int kc = 0; kc < 4; ++kc) {
      f16x8 kb[4];
#pragma unroll
      for (int kf = 0; kf < 4; ++kf) {
        int rr = kf * 16 + l15;
        int cl = kc * 4 + l4;
        kb[kf] = *(const f16x8*)((const char*)Ks[cur] + rr * 256 + ((cl ^ (rr & 7)) << 4));
      }
#pragma unroll
      for (int kf = 0; kf < 4; ++kf)
        sc[kf] = mfma16(kb[kf], qf[kc], sc[kf]);
    }
    __builtin_amdgcn_s_setprio(0);

    // tail mask on the final tile (raw-domain -inf surrogate)
    if (kt == ntiles - 1) {
#pragma unroll
      for (int kf = 0; kf < 4; ++kf)
#pragma unroll
        for (int r = 0; r < 4; ++r)
          if (kf * 16 + l4 * 4 + r >= lastlen) sc[kf][r] = -3e38f;
    }

    // lane-parallel online softmax (q = l15; keys split across l4 groups)
    float mx = sc[0][0];
#pragma unroll
    for (int kf = 0; kf < 4; ++kf)
#pragma unroll
      for (int r = 0; r < 4; ++r) mx = fmaxf(mx, sc[kf][r]);
    mx = fmaxf(mx, __shfl_xor(mx, 16));
    mx = fmaxf(mx, __shfl_xor(mx, 32));
    float al = 1.0f;
    if (__any(mx > rm)) {
      float nm = fmaxf(rm, mx);
      al = __builtin_amdgcn_exp2f((rm - nm) * sl2);
      rm = nm;
#pragma unroll
      for (int n = 0; n < 8; ++n)
#pragma unroll
        for (int r = 0; r < 4; ++r) o[n][r] *= al;
    }
    float nms = rm * sl2;
    float ts = 0.0f;
#pragma unroll
    for (int kf = 0; kf < 4; ++kf)
#pragma unroll
      for (int r = 0; r < 4; ++r) {
        float p = __builtin_amdgcn_exp2f(sc[kf][r] * sl2 - nms);
        sc[kf][r] = p;
        ts += p;
      }
    ts += __shfl_xor(ts, 16);
    ts += __shfl_xor(ts, 32);
    rl = rl * al + ts;

    // P fragments for PV (B-operand of 16x16x16): lane holds P[q=l15][k=l4*4+:4]
    f16x4 pb[4];
#pragma unroll
    for (int kf = 0; kf < 4; ++kf)
#pragma unroll
      for (int r = 0; r < 4; ++r) pb[kf][r] = (_Float16)sc[kf][r];

    // O^T += V^T P : A-operand = V^T[dv=n*16+l15][key=kf*16+l4*4+:4]
    __builtin_amdgcn_s_setprio(1);
#pragma unroll
    for (int n = 0; n < 8; ++n) {
      int dv = n * 16 + l15;
#pragma unroll
      for (int kf = 0; kf < 4; ++kf) {
        int phys = (kf * 2 + (l4 >> 1)) ^ (l15 & 7);
        f16x4 vb = *(const f16x4*)((const char*)Vst[cur] +
                                   dv * 128 + (phys << 4) + (l4 & 1) * 8);
        o[n] = mfma16k16(vb, pb[kf], o[n]);
      }
    }
    __builtin_amdgcn_s_setprio(0);
    __syncthreads();
  }

  // epilogue: divide by running sum, vector store fp32 (O^T layout -> full lines)
  float inv = 1.0f / rl;
  int qg = qt * 64 + w * 16 + l15;
#pragma unroll
  for (int n = 0; n < 8; ++n) {
    f32x4 ov;
#pragma unroll
    for (int r = 0; r < 4; ++r) ov[r] = o[n][r] * inv;
    *(f32x4*)(out + ((size_t)b * kMQ + qg) * kVC + h * 128 + n * 16 + l4 * 4) = ov;
  }
}

}  // namespace

extern "C" void kernel_launch(void* const* d_in, const int* in_sizes, int n_in,
                              void* d_out, int out_size, void* d_ws, size_t ws_size,
                              hipStream_t stream) {
  (void)in_sizes; (void)n_in; (void)out_size; (void)ws_size;
  const float* hs   = (const float*)d_in[0];
  const float* xin  = (const float*)d_in[1];
  const int*   msk  = (const int*)d_in[2];
  const float* ln1w = (const float*)d_in[3];
  const float* ln1b = (const float*)d_in[4];
  const float* ln2w = (const float*)d_in[5];
  const float* ln2b = (const float*)d_in[6];
  const float* Wq   = (const float*)d_in[7];
  const float* bq   = (const float*)d_in[8];
  const float* Wk   = (const float*)d_in[9];
  const float* bk   = (const float*)d_in[10];
  const float* Wv   = (const float*)d_in[11];
  const float* bv   = (const float*)d_in[12];
  float* out = (float*)d_out;

  char* ws = (char*)d_ws;
  _Float16* qbf  = (_Float16*)(ws + 0);          //  8,388,608 B [4096][1024]
  _Float16* kbf  = (_Float16*)(ws + 8388608);    // 33,554,432 B [16384][1024]
  _Float16* vT   = (_Float16*)(ws + 41943040);   // 33,554,432 B [1024][16384]
  _Float16* hsln = (_Float16*)(ws + 75497472);   //  8,388,608 B
  _Float16* kvln = (_Float16*)(ws + 83886080);   //  8,388,608 B
  _Float16* WqT  = (_Float16*)(ws + 92274688);   //  2,097,152 B [1024][1024]
  _Float16* WkT  = (_Float16*)(ws + 94371840);   //    524,288 B [1024][256]
  _Float16* WvT  = (_Float16*)(ws + 94896128);   //    524,288 B [1024][256]
  // total 95,420,416 B

  prep_all<<<8576, 256, 0, stream>>>(Wq, Wk, Wv, WqT, WkT, WvT,
                                     hs, ln1w, ln1b, hsln,
                                     xin, ln2w, ln2b, kvln);
  gemm_all<<<2304, 256, 0, stream>>>(hsln, WqT, bq, qbf,
                                     kvln, WkT, bk, kbf,
                                     WvT, bv, vT, msk);
  attn_kernel<<<512, 256, 0, stream>>>(qbf, kbf, vT, msk, out);
}